// Round 7
// baseline (425.374 us; speedup 1.0000x reference)
//
#include <hip/hip_runtime.h>

#define TT   2048
#define BSZ  64
#define DD0  256
#define DD1  128
#define DD2  3
#define NROW (DD1*BSZ)   // 8192 rows, r = o*64 + b

typedef __attribute__((ext_vector_type(8))) short short8;
typedef __attribute__((ext_vector_type(4))) float f32x4;
typedef __attribute__((ext_vector_type(4))) unsigned short us4;

__device__ __forceinline__ unsigned short f2b(float f) {
  unsigned u = __builtin_bit_cast(unsigned, f);
  unsigned r = (u + 0x7fffu + ((u >> 16) & 1u)) >> 16;   // RNE
  return (unsigned short)r;
}
__device__ __forceinline__ float b2f(unsigned short s) {
  unsigned u = ((unsigned)s) << 16;
  return __builtin_bit_cast(float, u);
}

// async global->LDS, 16B/lane. LDS ptr = WAVE-UNIFORM base; HW writes base+lane*16.
__device__ __forceinline__ void gload16(const void* g, void* l) {
  __builtin_amdgcn_global_load_lds(
      (const __attribute__((address_space(1))) unsigned int*)(unsigned long long)g,
      (__attribute__((address_space(3))) unsigned int*)(unsigned int)(unsigned long long)l,
      16, 0, 0);
}

// ------------------------------------------------------- transpose + f32->bf16
__global__ __launch_bounds__(256) void transpose_cvt(
    const float* __restrict__ src, unsigned short* __restrict__ dst,
    int R, int C, long sstride, long dstride)
{
  __shared__ float tile[64 * 65];
  const int z = blockIdx.z;
  src += (size_t)z * sstride;
  dst += (size_t)z * dstride;
  const int c0 = blockIdx.x * 64, r0 = blockIdx.y * 64;
  const int tid = threadIdx.x;
#pragma unroll
  for (int i = 0; i < 4; ++i) {
    int e = i * 256 + tid;
    int r = e >> 4, q = e & 15;
    float4 v = *(const float4*)&src[(size_t)(r0 + r) * C + c0 + q * 4];
    tile[r * 65 + q * 4 + 0] = v.x;
    tile[r * 65 + q * 4 + 1] = v.y;
    tile[r * 65 + q * 4 + 2] = v.z;
    tile[r * 65 + q * 4 + 3] = v.w;
  }
  __syncthreads();
#pragma unroll
  for (int i = 0; i < 4; ++i) {
    int e = i * 256 + tid;
    int c = e >> 4, q = e & 15;
    us4 o;
    o[0] = f2b(tile[(q * 4 + 0) * 65 + c]);
    o[1] = f2b(tile[(q * 4 + 1) * 65 + c]);
    o[2] = f2b(tile[(q * 4 + 2) * 65 + c]);
    o[3] = f2b(tile[(q * 4 + 3) * 65 + c]);
    *(us4*)&dst[(size_t)(c0 + c) * R + r0 + q * 4] = o;
  }
}

// ------------------------------------------------------------------ projection
__global__ __launch_bounds__(256) void proj_kernel(
    const float* __restrict__ W1, const unsigned short* __restrict__ Xt,
    unsigned short* __restrict__ Dout)
{
  __shared__ __align__(16) unsigned short Al[128 * 72];
  __shared__ __align__(16) unsigned short Bl[128 * 64];
  const int tid = threadIdx.x;
  const int b = blockIdx.y, t0 = blockIdx.x * 128;
  const int w = tid >> 6, l = tid & 63;
  const unsigned short* XtB = Xt + ((size_t)b * TT + t0) * DD0;

  f32x4 acc[8][2];
#pragma unroll
  for (int m = 0; m < 8; ++m)
#pragma unroll
    for (int n = 0; n < 2; ++n) acc[m][n] = f32x4{0.f, 0.f, 0.f, 0.f};

  for (int k0 = 0; k0 < DD0; k0 += 64) {
#pragma unroll
    for (int i = 0; i < 4; ++i) {
      int u = i * 256 + tid;
      int row = u >> 3, cg = u & 7;
      const float* s = &W1[row * DD0 + k0 + cg * 8];
      float4 v0 = *(const float4*)s;
      float4 v1 = *(const float4*)(s + 4);
      short8 p;
      p[0] = f2b(v0.x); p[1] = f2b(v0.y); p[2] = f2b(v0.z); p[3] = f2b(v0.w);
      p[4] = f2b(v1.x); p[5] = f2b(v1.y); p[6] = f2b(v1.z); p[7] = f2b(v1.w);
      *(short8*)&Al[row * 72 + cg * 8] = p;
    }
#pragma unroll
    for (int c = 0; c < 4; ++c) {
      int ob = (w * 4 + c) * 1024;
      int off = ob + l * 16;
      int row = off >> 7, c16 = (off >> 4) & 7;
      gload16((const char*)XtB + ((size_t)row * DD0 + k0) * 2 + ((c16 ^ (row & 7)) * 16),
              (char*)Bl + ob);
    }
    __syncthreads();
#pragma unroll
    for (int kk = 0; kk < 2; ++kk) {
      const int q = l >> 4;
      short8 bfr[2];
#pragma unroll
      for (int n = 0; n < 2; ++n) {
        int row = w * 32 + n * 16 + (l & 15);
        int c16 = (kk * 4 + q) ^ (row & 7);
        bfr[n] = *(const short8*)&Bl[row * 64 + c16 * 8];
      }
#pragma unroll
      for (int m = 0; m < 8; ++m) {
        int row = m * 16 + (l & 15);
        short8 a = *(const short8*)&Al[row * 72 + (kk * 4 + q) * 8];
        acc[m][0] = __builtin_amdgcn_mfma_f32_16x16x32_bf16(a, bfr[0], acc[m][0], 0, 0, 0);
        acc[m][1] = __builtin_amdgcn_mfma_f32_16x16x32_bf16(a, bfr[1], acc[m][1], 0, 0, 0);
      }
    }
    __syncthreads();
  }
#pragma unroll
  for (int m = 0; m < 8; ++m)
#pragma unroll
    for (int n = 0; n < 2; ++n)
#pragma unroll
      for (int r = 0; r < 4; ++r) {
        int o = m * 16 + (l >> 4) * 4 + r;
        int t = t0 + w * 32 + n * 16 + (l & 15);
        Dout[(size_t)(o * BSZ + b) * TT + t] = f2b(acc[m][n][r]);
      }
}

// ----------------------------------------------------------------- DFSMN stage
// BM=256, BN=256, BK=64; 512 thr = 8 waves (2Mx4N). 4 phases/K-tile, quadrant
// order (0,0),(0,1),(1,1),(1,0); b0 register-cached across P0..P3.
//
// DEEP-PREFETCH LEDGER (this round's change). Issues (1 ht/phase):
//   ht3(t+1)@P0(t), ht0(t+2)@P1(t), ht1(t+2)@P2(t), ht2(t+2)@P3(t)
//   => issue->read distance 7 phases; issue->force distance 5 phases (~1250cyc).
// Reads: ht0(t),ht1(t)@P0(t); ht2(t)@P1(t); ht3(t)@P2(t); P3 reads regs only.
// Gates (per-wave; barrier at end of gate phase orders vs other waves' reads):
//   G_P0(t) vmcnt(8): outstanding<=10 {ht2(t),ht3(t),ht0/1/2(t+1)} -> forces ht2(t)
//     (read at P1(t)).
//   G_P1(t) vmcnt(8): outstanding<=10 {ht3(t),ht0/1/2(t+1),ht3(t+1)} -> forces
//     ht3(t) (read at P2(t)).
//   G_P3(t) vmcnt(8): outstanding<=12 {ht0/1/2(t+1),ht3(t+1),ht0/1(t+2)} ->
//     forces ht0(t+1)+ht1(t+1) (read at P0(t+1)).
// Tail: G_P3(NT-2)=vmcnt(4); G_P0(NT-1)=vmcnt(2); G_P1(NT-1)=vmcnt(0); no
//   G_P3(NT-1). Prologue: stage ht0-3(0),ht0-2(1) (14 loads), vmcnt(10) forces
//   ht0/1(0), barrier.
// Space reuse (write@issue vs last ds_read, >=1 barrier + lgkmcnt drain between):
//   ht3(t+1)@P0(t) over ht3(t-1), last read P2(t-1) OK
//   ht0(t+2)@P1(t) over ht0(t),   last read P0(t)   OK
//   ht1(t+2)@P2(t) over ht1(t),   last read P0(t)   OK (P3 uses reg b0)
//   ht2(t+2)@P3(t) over ht2(t),   last read P1(t)   OK
template <int FIRST>
__global__ __launch_bounds__(512, 2) void stage_kernel(
    const unsigned short* __restrict__ Din,
    const unsigned short* __restrict__ Wt,
    unsigned short* __restrict__ M,
    unsigned short* __restrict__ Dout)
{
  __shared__ __align__(16) unsigned short lds[65536];   // A:[0,32K) B:[32K,64K) ushorts
  const int tid = threadIdx.x, w = tid >> 6, l = tid & 63;
  const int wr = w >> 2, wc = w & 3;
  // XCD chunking: xcd = linear%8 owns 8 s-tiles x 4 r-tiles
  const int L = blockIdx.y * 8 + blockIdx.x;
  const int s0 = ((L >> 3) & 7) * 256;
  const int r0 = ((L & 7) * 4 + (L >> 6)) * 256;
  const unsigned short* DinR = Din + (size_t)r0 * TT;
  const unsigned short* WtR  = Wt + (size_t)s0 * TT;
  const int q4 = l >> 4;
  const int swzg = ((l & 7) ^ (l >> 3)) << 4;   // inverse-swizzled global byte off
  const int NT = TT / 64;                       // 32 K-tiles

  f32x4 acc[8][4];                              // [ah*4+m][bh*2+n]
#pragma unroll
  for (int m = 0; m < 8; ++m)
#pragma unroll
    for (int n = 0; n < 4; ++n) acc[m][n] = f32x4{0.f, 0.f, 0.f, 0.f};

  // ht e: 0=Ah0 1=Bh0 2=Bh1 3=Ah1; half-tile = 128 rows x 64 k, 16 KB
  auto STAGE_HT = [&](int tau, int e) {
    if (tau >= NT) return;
    const int k0 = tau * 64, buf = tau & 1;
    const int isB = (e == 1 || e == 2);
    const int h = (e >= 2) ? 1 : 0;
    const unsigned short* base = isB ? WtR : DinR;
    unsigned short* ldst = &lds[(isB ? 32768 : 0) + buf * 16384 + h * 8192];
#pragma unroll
    for (int i = 0; i < 2; ++i) {
      int rr = i * 64 + w * 8 + (l >> 3);       // row within half
      gload16((const char*)(base + (size_t)(h * 128 + rr) * TT + k0) + swzg,
              (char*)ldst + (i * 512 + w * 64) * 16);
    }
  };
  auto LDA = [&](int buf, int ah, short8 (&ar)[4][2]) {
#pragma unroll
    for (int m = 0; m < 4; ++m) {
      int ra = wr * 64 + m * 16 + (l & 15);
#pragma unroll
      for (int kk = 0; kk < 2; ++kk)
        ar[m][kk] = *(const short8*)&lds[buf * 16384 + ah * 8192 + ra * 64 +
                                         (((kk * 4 + q4) ^ (ra & 7)) * 8)];
    }
  };
  auto LDB = [&](int buf, int bh, short8 (&br)[2][2]) {
#pragma unroll
    for (int n = 0; n < 2; ++n) {
      int rb = wc * 32 + n * 16 + (l & 15);
#pragma unroll
      for (int kk = 0; kk < 2; ++kk)
        br[n][kk] = *(const short8*)&lds[32768 + buf * 16384 + bh * 8192 + rb * 64 +
                                         (((kk * 4 + q4) ^ (rb & 7)) * 8)];
    }
  };
  auto MM = [&](int ah, int bh, short8 (&ar)[4][2], short8 (&br)[2][2]) {
    __builtin_amdgcn_s_setprio(1);
#pragma unroll
    for (int m = 0; m < 4; ++m)
#pragma unroll
      for (int n = 0; n < 2; ++n)
#pragma unroll
        for (int kk = 0; kk < 2; ++kk)
          acc[ah * 4 + m][bh * 2 + n] = __builtin_amdgcn_mfma_f32_16x16x32_bf16(
              ar[m][kk], br[n][kk], acc[ah * 4 + m][bh * 2 + n], 0, 0, 0);
    __builtin_amdgcn_s_setprio(0);
  };

  short8 a[4][2], b0[2][2], b1[2][2];

  // prologue: prime 7 half-tiles (14 loads); force ht0(0)+ht1(0); barrier.
  STAGE_HT(0, 0); STAGE_HT(0, 1); STAGE_HT(0, 2); STAGE_HT(0, 3);
  STAGE_HT(1, 0); STAGE_HT(1, 1); STAGE_HT(1, 2);
  asm volatile("s_waitcnt vmcnt(10)" ::: "memory");
  __builtin_amdgcn_s_barrier();

#pragma unroll 1
  for (int t = 0; t < NT; ++t) {
    const int buf = t & 1;
    // ---- P0: quadrant (0,0); gate forces ht2(t)
    if (t == NT - 1) { asm volatile("s_waitcnt vmcnt(2)" ::: "memory"); }
    else             { asm volatile("s_waitcnt vmcnt(8)" ::: "memory"); }
    LDA(buf, 0, a);
    LDB(buf, 0, b0);
    STAGE_HT(t + 1, 3);
    __builtin_amdgcn_s_barrier();
    asm volatile("s_waitcnt lgkmcnt(0)" ::: "memory");
    __builtin_amdgcn_sched_barrier(0);
    MM(0, 0, a, b0);
    __builtin_amdgcn_s_barrier();
    // ---- P1: quadrant (0,1); gate forces ht3(t)
    if (t == NT - 1) { asm volatile("s_waitcnt vmcnt(0)" ::: "memory"); }
    else             { asm volatile("s_waitcnt vmcnt(8)" ::: "memory"); }
    LDB(buf, 1, b1);
    STAGE_HT(t + 2, 0);
    __builtin_amdgcn_s_barrier();
    asm volatile("s_waitcnt lgkmcnt(0)" ::: "memory");
    __builtin_amdgcn_sched_barrier(0);
    MM(0, 1, a, b1);
    __builtin_amdgcn_s_barrier();
    // ---- P2: quadrant (1,1); no gate
    LDA(buf, 1, a);
    STAGE_HT(t + 2, 1);
    __builtin_amdgcn_s_barrier();
    asm volatile("s_waitcnt lgkmcnt(0)" ::: "memory");
    __builtin_amdgcn_sched_barrier(0);
    MM(1, 1, a, b1);
    __builtin_amdgcn_s_barrier();
    // ---- P3: quadrant (1,0), registers only; gate forces ht0/ht1(t+1)
    if (t == NT - 2)     { asm volatile("s_waitcnt vmcnt(4)" ::: "memory"); }
    else if (t < NT - 2) { asm volatile("s_waitcnt vmcnt(8)" ::: "memory"); }
    STAGE_HT(t + 2, 2);
    __builtin_amdgcn_s_barrier();
    MM(1, 0, a, b0);
    __builtin_amdgcn_s_barrier();
  }

  // ---- epilogue 1: softmax over each 64-batch group, stage probs (bf16) in LDS
  const int cc = l & 15;
#pragma unroll
  for (int j = 0; j < 4; ++j) {                 // j = bh*2+n
    const int bh = j >> 1, nn = j & 1;
    const int col = bh * 128 + wc * 32 + nn * 16 + cc;
    const int u = col >> 3;
#pragma unroll
    for (int ah = 0; ah < 2; ++ah) {            // batch group = ah*2 + wr
      float mx = -3.0e38f;
#pragma unroll
      for (int m = 0; m < 4; ++m)
#pragma unroll
        for (int r = 0; r < 4; ++r) mx = fmaxf(mx, acc[ah * 4 + m][j][r]);
      mx = fmaxf(mx, __shfl_xor(mx, 16));
      mx = fmaxf(mx, __shfl_xor(mx, 32));
      float pr[4][4];
      float sm = 0.f;
#pragma unroll
      for (int m = 0; m < 4; ++m)
#pragma unroll
        for (int r = 0; r < 4; ++r) { pr[m][r] = __expf(acc[ah * 4 + m][j][r] - mx); sm += pr[m][r]; }
      sm += __shfl_xor(sm, 16);
      sm += __shfl_xor(sm, 32);
      const float rs = 1.f / sm;
#pragma unroll
      for (int m = 0; m < 4; ++m)
#pragma unroll
        for (int r = 0; r < 4; ++r) {
          int row = ah * 128 + wr * 64 + m * 16 + q4 * 4 + r;
          lds[row * 256 + (((u ^ ((row >> 2) & 7)) << 3) | (col & 7))] = f2b(pr[m][r] * rs);
        }
    }
  }
  asm volatile("s_waitcnt lgkmcnt(0)" ::: "memory");
  __builtin_amdgcn_s_barrier();

  // ---- epilogue 2: fully-coalesced stream: Mn = D*A + Mprev; Dout = D + Mn
  // 256 rows x 32 short8-units = 8192 units over 512 threads -> 16 iters.
#pragma unroll 4
  for (int i = 0; i < 16; ++i) {
    int unit = i * 512 + tid;
    int row = unit >> 5, u = unit & 31;
    short8 a8 = *(const short8*)&lds[row * 256 + ((u ^ ((row >> 2) & 7)) << 3)];
    size_t g = (size_t)(r0 + row) * TT + s0 + u * 8;
    short8 d8 = *(const short8*)&Din[g];
    short8 mp8 = {};
    if (!FIRST) mp8 = *(const short8*)&M[g];
    short8 mo, dn;
#pragma unroll
    for (int j = 0; j < 8; ++j) {
      float d = b2f((unsigned short)d8[j]);
      float aa = b2f((unsigned short)a8[j]);
      float mp = FIRST ? 0.f : b2f((unsigned short)mp8[j]);
      float mn = fmaf(d, aa, mp);
      mo[j] = (short)f2b(mn);
      dn[j] = (short)f2b(d + mn);
    }
    *(short8*)&M[g] = mo;
    *(short8*)&Dout[g] = dn;
  }
}

// ---------------------------------------------------------------- output proj
__global__ __launch_bounds__(256) void out_proj(
    const unsigned short* __restrict__ D4, const float* __restrict__ W2,
    const float* __restrict__ Bb, float* __restrict__ Y)
{
  const int r = blockIdx.x;          // o*64 + b
  const int o = r >> 6, b = r & 63;
  const int tid = threadIdx.x;
  float p0 = 0.f, p1 = 0.f, p2 = 0.f;
  for (int t = tid; t < TT; t += 256) {
    float d = b2f(D4[(size_t)r * TT + t]);
    p0 = fmaf(d, W2[t * 3 + 0], p0);
    p1 = fmaf(d, W2[t * 3 + 1], p1);
    p2 = fmaf(d, W2[t * 3 + 2], p2);
  }
#pragma unroll
  for (int off = 1; off < 64; off <<= 1) {
    p0 += __shfl_xor(p0, off);
    p1 += __shfl_xor(p1, off);
    p2 += __shfl_xor(p2, off);
  }
  __shared__ float red[4][3];
  const int w = tid >> 6, l = tid & 63;
  if (l == 0) { red[w][0] = p0; red[w][1] = p1; red[w][2] = p2; }
  __syncthreads();
  if (tid < 3) {
    float s = red[0][tid] + red[1][tid] + red[2][tid] + red[3][tid];
    Y[(size_t)(b * DD1 + o) * DD2 + tid] = s + Bb[o * DD2 + tid];
  }
}

// -------------------------------------------------------------------- launch
extern "C" void kernel_launch(void* const* d_in, const int* in_sizes, int n_in,
                              void* d_out, int out_size, void* d_ws, size_t ws_size,
                              hipStream_t stream)
{
  const float* X  = (const float*)d_in[0];
  const float* W1 = (const float*)d_in[1];
  const float* DW[4] = {(const float*)d_in[2], (const float*)d_in[3],
                        (const float*)d_in[4], (const float*)d_in[5]};
  const float* W2 = (const float*)d_in[6];
  const float* Bb = (const float*)d_in[7];
  float* Y = (float*)d_out;

  unsigned short* ws = (unsigned short*)d_ws;
  unsigned short* Wt[4];
  for (int i = 0; i < 4; ++i) Wt[i] = ws + (size_t)i * TT * TT;          // 32 MiB
  unsigned short* Dbuf0 = ws + (size_t)4 * TT * TT;                      // +32M
  unsigned short* Xt    = Dbuf0 + (size_t)NROW * TT;                     // +64M
  unsigned short* Dbuf1 = Xt;                                            // alias
  unsigned short* Mbuf  = Xt + (size_t)NROW * TT;                        // +96M

  dim3 blk(256);
  for (int i = 0; i < 4; ++i)
    transpose_cvt<<<dim3(TT / 64, TT / 64, 1), blk, 0, stream>>>(DW[i], Wt[i], TT, TT, 0, 0);
  transpose_cvt<<<dim3(TT / 64, DD0 / 64, BSZ), blk, 0, stream>>>(
      X, Xt, DD0, TT, (long)DD0 * TT, (long)TT * DD0);

  proj_kernel<<<dim3(TT / 128, BSZ), blk, 0, stream>>>(W1, Xt, Dbuf0);

  dim3 sblk(512);
  dim3 sgrid(TT / 256, NROW / 256);
  stage_kernel<1><<<sgrid, sblk, 0, stream>>>(Dbuf0, Wt[0], Mbuf, Dbuf1);
  stage_kernel<0><<<sgrid, sblk, 0, stream>>>(Dbuf1, Wt[1], Mbuf, Dbuf0);
  stage_kernel<0><<<sgrid, sblk, 0, stream>>>(Dbuf0, Wt[2], Mbuf, Dbuf1);
  stage_kernel<0><<<sgrid, sblk, 0, stream>>>(Dbuf1, Wt[3], Mbuf, Dbuf0);

  out_proj<<<dim3(NROW), blk, 0, stream>>>(Dbuf0, W2, Bb, Y);
}

// Round 8
// 403.642 us; speedup vs baseline: 1.0538x; 1.0538x over previous
//
#include <hip/hip_runtime.h>

#define TT   2048
#define BSZ  64
#define DD0  256
#define DD1  128
#define DD2  3
#define NROW (DD1*BSZ)   // 8192 rows, r = o*64 + b

typedef __attribute__((ext_vector_type(8))) short short8;
typedef __attribute__((ext_vector_type(4))) float f32x4;
typedef __attribute__((ext_vector_type(4))) unsigned short us4;

__device__ __forceinline__ unsigned short f2b(float f) {
  unsigned u = __builtin_bit_cast(unsigned, f);
  unsigned r = (u + 0x7fffu + ((u >> 16) & 1u)) >> 16;   // RNE
  return (unsigned short)r;
}
__device__ __forceinline__ float b2f(unsigned short s) {
  unsigned u = ((unsigned)s) << 16;
  return __builtin_bit_cast(float, u);
}

// async global->LDS, 16B/lane. LDS ptr = WAVE-UNIFORM base; HW writes base+lane*16.
__device__ __forceinline__ void gload16(const void* g, void* l) {
  __builtin_amdgcn_global_load_lds(
      (const __attribute__((address_space(1))) unsigned int*)(unsigned long long)g,
      (__attribute__((address_space(3))) unsigned int*)(unsigned int)(unsigned long long)l,
      16, 0, 0);
}

// ------------------------------------------------------- transpose + f32->bf16
__global__ __launch_bounds__(256) void transpose_cvt(
    const float* __restrict__ src, unsigned short* __restrict__ dst,
    int R, int C, long sstride, long dstride)
{
  __shared__ float tile[64 * 65];
  const int z = blockIdx.z;
  src += (size_t)z * sstride;
  dst += (size_t)z * dstride;
  const int c0 = blockIdx.x * 64, r0 = blockIdx.y * 64;
  const int tid = threadIdx.x;
#pragma unroll
  for (int i = 0; i < 4; ++i) {
    int e = i * 256 + tid;
    int r = e >> 4, q = e & 15;
    float4 v = *(const float4*)&src[(size_t)(r0 + r) * C + c0 + q * 4];
    tile[r * 65 + q * 4 + 0] = v.x;
    tile[r * 65 + q * 4 + 1] = v.y;
    tile[r * 65 + q * 4 + 2] = v.z;
    tile[r * 65 + q * 4 + 3] = v.w;
  }
  __syncthreads();
#pragma unroll
  for (int i = 0; i < 4; ++i) {
    int e = i * 256 + tid;
    int c = e >> 4, q = e & 15;
    us4 o;
    o[0] = f2b(tile[(q * 4 + 0) * 65 + c]);
    o[1] = f2b(tile[(q * 4 + 1) * 65 + c]);
    o[2] = f2b(tile[(q * 4 + 2) * 65 + c]);
    o[3] = f2b(tile[(q * 4 + 3) * 65 + c]);
    *(us4*)&dst[(size_t)(c0 + c) * R + r0 + q * 4] = o;
  }
}

// ------------------------------------------------------------------ projection
__global__ __launch_bounds__(256) void proj_kernel(
    const float* __restrict__ W1, const unsigned short* __restrict__ Xt,
    unsigned short* __restrict__ Dout)
{
  __shared__ __align__(16) unsigned short Al[128 * 72];
  __shared__ __align__(16) unsigned short Bl[128 * 64];
  const int tid = threadIdx.x;
  const int b = blockIdx.y, t0 = blockIdx.x * 128;
  const int w = tid >> 6, l = tid & 63;
  const unsigned short* XtB = Xt + ((size_t)b * TT + t0) * DD0;

  f32x4 acc[8][2];
#pragma unroll
  for (int m = 0; m < 8; ++m)
#pragma unroll
    for (int n = 0; n < 2; ++n) acc[m][n] = f32x4{0.f, 0.f, 0.f, 0.f};

  for (int k0 = 0; k0 < DD0; k0 += 64) {
#pragma unroll
    for (int i = 0; i < 4; ++i) {
      int u = i * 256 + tid;
      int row = u >> 3, cg = u & 7;
      const float* s = &W1[row * DD0 + k0 + cg * 8];
      float4 v0 = *(const float4*)s;
      float4 v1 = *(const float4*)(s + 4);
      short8 p;
      p[0] = f2b(v0.x); p[1] = f2b(v0.y); p[2] = f2b(v0.z); p[3] = f2b(v0.w);
      p[4] = f2b(v1.x); p[5] = f2b(v1.y); p[6] = f2b(v1.z); p[7] = f2b(v1.w);
      *(short8*)&Al[row * 72 + cg * 8] = p;
    }
#pragma unroll
    for (int c = 0; c < 4; ++c) {
      int ob = (w * 4 + c) * 1024;
      int off = ob + l * 16;
      int row = off >> 7, c16 = (off >> 4) & 7;
      gload16((const char*)XtB + ((size_t)row * DD0 + k0) * 2 + ((c16 ^ (row & 7)) * 16),
              (char*)Bl + ob);
    }
    __syncthreads();
#pragma unroll
    for (int kk = 0; kk < 2; ++kk) {
      const int q = l >> 4;
      short8 bfr[2];
#pragma unroll
      for (int n = 0; n < 2; ++n) {
        int row = w * 32 + n * 16 + (l & 15);
        int c16 = (kk * 4 + q) ^ (row & 7);
        bfr[n] = *(const short8*)&Bl[row * 64 + c16 * 8];
      }
#pragma unroll
      for (int m = 0; m < 8; ++m) {
        int row = m * 16 + (l & 15);
        short8 a = *(const short8*)&Al[row * 72 + (kk * 4 + q) * 8];
        acc[m][0] = __builtin_amdgcn_mfma_f32_16x16x32_bf16(a, bfr[0], acc[m][0], 0, 0, 0);
        acc[m][1] = __builtin_amdgcn_mfma_f32_16x16x32_bf16(a, bfr[1], acc[m][1], 0, 0, 0);
      }
    }
    __syncthreads();
  }
#pragma unroll
  for (int m = 0; m < 8; ++m)
#pragma unroll
    for (int n = 0; n < 2; ++n)
#pragma unroll
      for (int r = 0; r < 4; ++r) {
        int o = m * 16 + (l >> 4) * 4 + r;
        int t = t0 + w * 32 + n * 16 + (l & 15);
        Dout[(size_t)(o * BSZ + b) * TT + t] = f2b(acc[m][n][r]);
      }
}

// ----------------------------------------------------------------- DFSMN stage
// BM=256, BN=256, BK=64; 512 thr = 8 waves (2Mx4N), 128x64 out/wave.
// MINIMAL-SYNC K-loop: ONE barrier per K-tile. Per tile t:
//   STAGE_ALL(t+1) -> buf^1   (8 gloads; buf^1's last reads retired before the
//                              barrier that ended tile t-1 -> no WAR hazard)
//   issue b0,a0,b1 ds_reads from buf; MM00, MM01 (compiler inserts fine-grained
//   lgkmcnt for read->MFMA deps); reload a1 over a0 (dead after MM01); MM11,MM10.
//   vmcnt(0)                  (forces ht(t+1); window = full tile >> HBM latency)
//   s_barrier                 (cross-wave: everyone's staging landed; everyone's
//                              reads of buf retired -- in-order lgkm retirement
//                              means waiting MM10's operands retired all 24)
// No intra-tile barriers -> waves drift within the tile, LDS read bursts overlap
// other waves' MFMA; 2 waves/SIMD co-schedule read/MFMA pipes.
template <int FIRST>
__global__ __launch_bounds__(512, 2) void stage_kernel(
    const unsigned short* __restrict__ Din,
    const unsigned short* __restrict__ Wt,
    unsigned short* __restrict__ M,
    unsigned short* __restrict__ Dout)
{
  __shared__ __align__(16) unsigned short lds[65536];   // A:[0,32K) B:[32K,64K) ushorts
  const int tid = threadIdx.x, w = tid >> 6, l = tid & 63;
  const int wr = w >> 2, wc = w & 3;
  // XCD chunking: xcd = linear%8 owns 8 s-tiles x 4 r-tiles
  const int L = blockIdx.y * 8 + blockIdx.x;
  const int s0 = ((L >> 3) & 7) * 256;
  const int r0 = ((L & 7) * 4 + (L >> 6)) * 256;
  const unsigned short* DinR = Din + (size_t)r0 * TT;
  const unsigned short* WtR  = Wt + (size_t)s0 * TT;
  const int q4 = l >> 4;
  const int swzg = ((l & 7) ^ (l >> 3)) << 4;   // inverse-swizzled global byte off
  const int NT = TT / 64;                       // 32 K-tiles

  f32x4 acc[8][4];                              // [ah*4+m][bh*2+n]
#pragma unroll
  for (int m = 0; m < 8; ++m)
#pragma unroll
    for (int n = 0; n < 4; ++n) acc[m][n] = f32x4{0.f, 0.f, 0.f, 0.f};

  // ht e: 0=Ah0 1=Bh0 2=Bh1 3=Ah1; half-tile = 128 rows x 64 k, 16 KB
  auto STAGE_HT = [&](int tau, int e) {
    if (tau >= NT) return;
    const int k0 = tau * 64, buf = tau & 1;
    const int isB = (e == 1 || e == 2);
    const int h = (e >= 2) ? 1 : 0;
    const unsigned short* base = isB ? WtR : DinR;
    unsigned short* ldst = &lds[(isB ? 32768 : 0) + buf * 16384 + h * 8192];
#pragma unroll
    for (int i = 0; i < 2; ++i) {
      int rr = i * 64 + w * 8 + (l >> 3);       // row within half
      gload16((const char*)(base + (size_t)(h * 128 + rr) * TT + k0) + swzg,
              (char*)ldst + (i * 512 + w * 64) * 16);
    }
  };
  auto LDA = [&](int buf, int ah, short8 (&ar)[4][2]) {
#pragma unroll
    for (int m = 0; m < 4; ++m) {
      int ra = wr * 64 + m * 16 + (l & 15);
#pragma unroll
      for (int kk = 0; kk < 2; ++kk)
        ar[m][kk] = *(const short8*)&lds[buf * 16384 + ah * 8192 + ra * 64 +
                                         (((kk * 4 + q4) ^ (ra & 7)) * 8)];
    }
  };
  auto LDB = [&](int buf, int bh, short8 (&br)[2][2]) {
#pragma unroll
    for (int n = 0; n < 2; ++n) {
      int rb = wc * 32 + n * 16 + (l & 15);
#pragma unroll
      for (int kk = 0; kk < 2; ++kk)
        br[n][kk] = *(const short8*)&lds[32768 + buf * 16384 + bh * 8192 + rb * 64 +
                                         (((kk * 4 + q4) ^ (rb & 7)) * 8)];
    }
  };
  auto MM = [&](int ah, int bh, short8 (&ar)[4][2], short8 (&br)[2][2]) {
    __builtin_amdgcn_s_setprio(1);
#pragma unroll
    for (int m = 0; m < 4; ++m)
#pragma unroll
      for (int n = 0; n < 2; ++n)
#pragma unroll
        for (int kk = 0; kk < 2; ++kk)
          acc[ah * 4 + m][bh * 2 + n] = __builtin_amdgcn_mfma_f32_16x16x32_bf16(
              ar[m][kk], br[n][kk], acc[ah * 4 + m][bh * 2 + n], 0, 0, 0);
    __builtin_amdgcn_s_setprio(0);
  };

  short8 a[4][2], b0[2][2], b1[2][2];

  // prologue: stage K-tile 0, force it, barrier.
  STAGE_HT(0, 0); STAGE_HT(0, 1); STAGE_HT(0, 2); STAGE_HT(0, 3);
  asm volatile("s_waitcnt vmcnt(0)" ::: "memory");
  __builtin_amdgcn_s_barrier();

#pragma unroll 1
  for (int t = 0; t < NT; ++t) {
    const int buf = t & 1;
    // stage next tile first: max landing window (full tile)
    STAGE_HT(t + 1, 0); STAGE_HT(t + 1, 1);
    STAGE_HT(t + 1, 2); STAGE_HT(t + 1, 3);
    // issue reads; compiler inserts fine-grained lgkmcnt before dependent MFMAs
    LDB(buf, 0, b0);
    LDA(buf, 0, a);
    LDB(buf, 1, b1);
    MM(0, 0, a, b0);
    MM(0, 1, a, b1);
    LDA(buf, 1, a);          // a0 dead after MM01; reuse registers
    MM(1, 1, a, b1);
    MM(1, 0, a, b0);
    asm volatile("s_waitcnt vmcnt(0)" ::: "memory");   // ht(t+1) landed (wide window)
    __builtin_amdgcn_s_barrier();
  }

  // ---- epilogue 1: softmax over each 64-batch group, stage probs (bf16) in LDS
  const int cc = l & 15;
#pragma unroll
  for (int j = 0; j < 4; ++j) {                 // j = bh*2+n
    const int bh = j >> 1, nn = j & 1;
    const int col = bh * 128 + wc * 32 + nn * 16 + cc;
    const int u = col >> 3;
#pragma unroll
    for (int ah = 0; ah < 2; ++ah) {            // batch group = ah*2 + wr
      float mx = -3.0e38f;
#pragma unroll
      for (int m = 0; m < 4; ++m)
#pragma unroll
        for (int r = 0; r < 4; ++r) mx = fmaxf(mx, acc[ah * 4 + m][j][r]);
      mx = fmaxf(mx, __shfl_xor(mx, 16));
      mx = fmaxf(mx, __shfl_xor(mx, 32));
      float pr[4][4];
      float sm = 0.f;
#pragma unroll
      for (int m = 0; m < 4; ++m)
#pragma unroll
        for (int r = 0; r < 4; ++r) { pr[m][r] = __expf(acc[ah * 4 + m][j][r] - mx); sm += pr[m][r]; }
      sm += __shfl_xor(sm, 16);
      sm += __shfl_xor(sm, 32);
      const float rs = 1.f / sm;
#pragma unroll
      for (int m = 0; m < 4; ++m)
#pragma unroll
        for (int r = 0; r < 4; ++r) {
          int row = ah * 128 + wr * 64 + m * 16 + q4 * 4 + r;
          lds[row * 256 + (((u ^ ((row >> 2) & 7)) << 3) | (col & 7))] = f2b(pr[m][r] * rs);
        }
    }
  }
  asm volatile("s_waitcnt lgkmcnt(0)" ::: "memory");
  __builtin_amdgcn_s_barrier();

  // ---- epilogue 2: fully-coalesced stream: Mn = D*A + Mprev; Dout = D + Mn
  // 256 rows x 32 short8-units = 8192 units over 512 threads -> 16 iters.
#pragma unroll 4
  for (int i = 0; i < 16; ++i) {
    int unit = i * 512 + tid;
    int row = unit >> 5, u = unit & 31;
    short8 a8 = *(const short8*)&lds[row * 256 + ((u ^ ((row >> 2) & 7)) << 3)];
    size_t g = (size_t)(r0 + row) * TT + s0 + u * 8;
    short8 d8 = *(const short8*)&Din[g];
    short8 mp8 = {};
    if (!FIRST) mp8 = *(const short8*)&M[g];
    short8 mo, dn;
#pragma unroll
    for (int j = 0; j < 8; ++j) {
      float d = b2f((unsigned short)d8[j]);
      float aa = b2f((unsigned short)a8[j]);
      float mp = FIRST ? 0.f : b2f((unsigned short)mp8[j]);
      float mn = fmaf(d, aa, mp);
      mo[j] = (short)f2b(mn);
      dn[j] = (short)f2b(d + mn);
    }
    *(short8*)&M[g] = mo;
    *(short8*)&Dout[g] = dn;
  }
}

// ---------------------------------------------------------------- output proj
__global__ __launch_bounds__(256) void out_proj(
    const unsigned short* __restrict__ D4, const float* __restrict__ W2,
    const float* __restrict__ Bb, float* __restrict__ Y)
{
  const int r = blockIdx.x;          // o*64 + b
  const int o = r >> 6, b = r & 63;
  const int tid = threadIdx.x;
  float p0 = 0.f, p1 = 0.f, p2 = 0.f;
  for (int t = tid; t < TT; t += 256) {
    float d = b2f(D4[(size_t)r * TT + t]);
    p0 = fmaf(d, W2[t * 3 + 0], p0);
    p1 = fmaf(d, W2[t * 3 + 1], p1);
    p2 = fmaf(d, W2[t * 3 + 2], p2);
  }
#pragma unroll
  for (int off = 1; off < 64; off <<= 1) {
    p0 += __shfl_xor(p0, off);
    p1 += __shfl_xor(p1, off);
    p2 += __shfl_xor(p2, off);
  }
  __shared__ float red[4][3];
  const int w = tid >> 6, l = tid & 63;
  if (l == 0) { red[w][0] = p0; red[w][1] = p1; red[w][2] = p2; }
  __syncthreads();
  if (tid < 3) {
    float s = red[0][tid] + red[1][tid] + red[2][tid] + red[3][tid];
    Y[(size_t)(b * DD1 + o) * DD2 + tid] = s + Bb[o * DD2 + tid];
  }
}

// -------------------------------------------------------------------- launch
extern "C" void kernel_launch(void* const* d_in, const int* in_sizes, int n_in,
                              void* d_out, int out_size, void* d_ws, size_t ws_size,
                              hipStream_t stream)
{
  const float* X  = (const float*)d_in[0];
  const float* W1 = (const float*)d_in[1];
  const float* DW[4] = {(const float*)d_in[2], (const float*)d_in[3],
                        (const float*)d_in[4], (const float*)d_in[5]};
  const float* W2 = (const float*)d_in[6];
  const float* Bb = (const float*)d_in[7];
  float* Y = (float*)d_out;

  unsigned short* ws = (unsigned short*)d_ws;
  unsigned short* Wt[4];
  for (int i = 0; i < 4; ++i) Wt[i] = ws + (size_t)i * TT * TT;          // 32 MiB
  unsigned short* Dbuf0 = ws + (size_t)4 * TT * TT;                      // +32M
  unsigned short* Xt    = Dbuf0 + (size_t)NROW * TT;                     // +64M
  unsigned short* Dbuf1 = Xt;                                            // alias
  unsigned short* Mbuf  = Xt + (size_t)NROW * TT;                        // +96M

  dim3 blk(256);
  for (int i = 0; i < 4; ++i)
    transpose_cvt<<<dim3(TT / 64, TT / 64, 1), blk, 0, stream>>>(DW[i], Wt[i], TT, TT, 0, 0);
  transpose_cvt<<<dim3(TT / 64, DD0 / 64, BSZ), blk, 0, stream>>>(
      X, Xt, DD0, TT, (long)DD0 * TT, (long)TT * DD0);

  proj_kernel<<<dim3(TT / 128, BSZ), blk, 0, stream>>>(W1, Xt, Dbuf0);

  dim3 sblk(512);
  dim3 sgrid(TT / 256, NROW / 256);
  stage_kernel<1><<<sgrid, sblk, 0, stream>>>(Dbuf0, Wt[0], Mbuf, Dbuf1);
  stage_kernel<0><<<sgrid, sblk, 0, stream>>>(Dbuf1, Wt[1], Mbuf, Dbuf0);
  stage_kernel<0><<<sgrid, sblk, 0, stream>>>(Dbuf0, Wt[2], Mbuf, Dbuf1);
  stage_kernel<0><<<sgrid, sblk, 0, stream>>>(Dbuf1, Wt[3], Mbuf, Dbuf0);

  out_proj<<<dim3(NROW), blk, 0, stream>>>(Dbuf0, W2, Bb, Y);
}